// Round 7
// baseline (146.405 us; speedup 1.0000x reference)
//
#include <hip/hip_runtime.h>
#include <hip/hip_fp16.h>
#include <math.h>

#define D_FEAT 128
#define NB 256          // src buckets; bucket = src >> shift, < NB
#define SCH 4096        // edges per scatter block (391 blocks at E=1.6M)

typedef _Float16 f16x2 __attribute__((ext_vector_type(2)));
struct alignas(16) h8v { f16x2 h[4]; };   // 8 halves = 16B

__device__ __forceinline__ float dot8(const h8v& a, const h8v& b, float acc) {
#if __has_builtin(__builtin_amdgcn_fdot2)
#pragma unroll
    for (int k = 0; k < 4; ++k)
        acc = __builtin_amdgcn_fdot2(a.h[k], b.h[k], acc, false);
#else
#pragma unroll
    for (int k = 0; k < 4; ++k) {
        acc += (float)a.h[k].x * (float)b.h[k].x;
        acc += (float)a.h[k].y * (float)b.h[k].y;
    }
#endif
    return acc;
}

__device__ __forceinline__ float sigmoid_fast(float x) {
    return 1.0f / (1.0f + __builtin_exp2f(-1.44269504f * x));
}

// ---------------- fp32 -> fp16 conversion of x into workspace ----------------
__global__ __launch_bounds__(256) void convert_x_fp16_kernel(
    const float* __restrict__ x, __half* __restrict__ xh, int n_elems)
{
    int i = blockIdx.x * blockDim.x + threadIdx.x;
    int base = i * 8;
    if (base >= n_elems) return;
    const float4* p = reinterpret_cast<const float4*>(x + base);
    float4 f0 = p[0];
    float4 f1 = p[1];
    __half2 h[4];
    h[0] = __floats2half2_rn(f0.x, f0.y);
    h[1] = __floats2half2_rn(f0.z, f0.w);
    h[2] = __floats2half2_rn(f1.x, f1.y);
    h[3] = __floats2half2_rn(f1.z, f1.w);
    *reinterpret_cast<float4*>(xh + base) = *reinterpret_cast<float4*>(h);
}

// ---------------- histogram of src buckets ----------------
__global__ __launch_bounds__(256) void hist_kernel(
    const int* __restrict__ ei, int n_edges, int shift, int* __restrict__ hist)
{
    __shared__ int h[NB];
    for (int i = threadIdx.x; i < NB; i += 256) h[i] = 0;
    __syncthreads();
    for (int e = blockIdx.x * 256 + threadIdx.x; e < n_edges; e += gridDim.x * 256)
        atomicAdd(&h[ei[e] >> shift], 1);
    __syncthreads();
    for (int i = threadIdx.x; i < NB; i += 256) {
        int c = h[i];
        if (c) atomicAdd(&hist[i], c);
    }
}

// scan (1 block, NB threads): exclusive prefix -> cursor; edge-octile
// boundaries at bucket granularity -> estart[0..8] (balanced XCD regions).
__global__ __launch_bounds__(NB) void scan_kernel(
    const int* __restrict__ hist, int* __restrict__ cursor,
    int* __restrict__ estart, int n_edges)
{
    __shared__ int tmp[NB];
    const int t = threadIdx.x;
    int own = hist[t];
    tmp[t] = own;
    __syncthreads();
    for (int off = 1; off < NB; off <<= 1) {
        int v = (t >= off) ? tmp[t - off] : 0;
        __syncthreads();
        tmp[t] += v;
        __syncthreads();
    }
    int excl = tmp[t] - own;
    cursor[t] = excl;
#pragma unroll
    for (int k = 1; k < 8; ++k) {
        long target = ((long)n_edges * k) >> 3;
        if (own > 0 && (long)excl <= target && target < (long)excl + own)
            estart[k] = excl;
    }
    if (t == 0) { estart[0] = 0; estart[8] = n_edges; }
}

// ---------------- scatter: (s,d) int2 + e int, sorted by src bucket ----------
__global__ __launch_bounds__(256) void scatter_kernel(
    const int* __restrict__ ei, int n_edges, int shift, int* __restrict__ cursor,
    int2* __restrict__ sd, int* __restrict__ se)
{
    __shared__ int h[NB];     // pass A: counts; pass B: local cursors
    __shared__ int base[NB];
    const int t = threadIdx.x;
    for (int i = t; i < NB; i += 256) h[i] = 0;
    __syncthreads();

    const int c0 = blockIdx.x * SCH;
    const int cend = min(n_edges, c0 + SCH);

    int s[16], d[16];
#pragma unroll 16
    for (int i = 0; i < 16; ++i) {
        int e = c0 + t + i * 256;
        bool v = e < cend;
        s[i] = v ? ei[e] : 0;
        d[i] = v ? ei[n_edges + e] : 0;
        if (v) atomicAdd(&h[s[i] >> shift], 1);
    }
    __syncthreads();
    for (int i = t; i < NB; i += 256) {
        int c = h[i];
        base[i] = c ? atomicAdd(&cursor[i], c) : 0;
        h[i] = 0;
    }
    __syncthreads();
#pragma unroll 16
    for (int i = 0; i < 16; ++i) {
        int e = c0 + t + i * 256;
        if (e < cend) {
            int b = s[i] >> shift;
            int loc = atomicAdd(&h[b], 1);
            int pos = base[b] + loc;
            int2 v; v.x = s[i]; v.y = d[i];
            sd[pos] = v;
            se[pos] = e;
        }
    }
}

// ---------------- sorted fp16 gather + dot + sigmoid, XCD-pinned -------------
// bid&7 selects the XCD (round-robin dispatch, validated rounds 5/6); each
// XCD's blocks walk a contiguous region of the src-sorted edge list, so the
// active fine-bucket's ~128KB src-row set stays L2-hot. 16-lane group per
// edge, 2 edges per group.
__global__ __launch_bounds__(256) void edge_dot_sigmoid_sorted_kernel(
    const __half* __restrict__ xh,
    const int2* __restrict__ sd,
    const int* __restrict__ se,
    const int* __restrict__ estart,
    float* __restrict__ out,
    int npb)
{
    const int k  = blockIdx.x & 7;        // XCD id under round-robin dispatch
    const int ib = blockIdx.x >> 3;       // block index within region
    const int st = estart[k];
    const int en = estart[k + 1];

    const int lane = threadIdx.x & 15;
    const int grp  = threadIdx.x >> 4;

    const h8v* __restrict__ xrow = reinterpret_cast<const h8v*>(xh); // 16/row

    for (int p = st + ib * 32; p < en; p += npb * 32) {
        const int e0 = p + grp;
        const int e1 = p + 16 + grp;
        if (e0 >= en) break;

        int2 t0 = sd[e0];
        const bool has1 = (e1 < en);
        int2 t1 = has1 ? sd[e1] : t0;

        h8v a0 = xrow[(size_t)t0.x * 16 + lane];
        h8v b0 = xrow[(size_t)t0.y * 16 + lane];
        h8v a1 = xrow[(size_t)t1.x * 16 + lane];
        h8v b1 = xrow[(size_t)t1.y * 16 + lane];

        float acc0 = dot8(a0, b0, 0.f);
        float acc1 = dot8(a1, b1, 0.f);

        acc0 += __shfl_xor(acc0, 1, 16);
        acc0 += __shfl_xor(acc0, 2, 16);
        acc0 += __shfl_xor(acc0, 4, 16);
        acc0 += __shfl_xor(acc0, 8, 16);

        acc1 += __shfl_xor(acc1, 1, 16);
        acc1 += __shfl_xor(acc1, 2, 16);
        acc1 += __shfl_xor(acc1, 4, 16);
        acc1 += __shfl_xor(acc1, 8, 16);

        if (lane == 0) {
            out[se[e0]] = sigmoid_fast(acc0);
            if (has1) out[se[e1]] = sigmoid_fast(acc1);
        }
    }
}

// ---------------- unsorted fp16 path (fallback if ws too small for sort) ----
__global__ __launch_bounds__(256) void edge_dot_sigmoid_fp16_kernel(
    const __half* __restrict__ xh,
    const int* __restrict__ ei,
    float* __restrict__ out,
    int n_edges)
{
    const int lane = threadIdx.x & 15;
    const int grp  = threadIdx.x >> 4;
    const int base = blockIdx.x * 32;
    const int e0 = base + grp;
    const int e1 = base + 16 + grp;
    if (e0 >= n_edges) return;

    const int s0 = ei[e0];
    const int d0 = ei[n_edges + e0];
    const bool has1 = (e1 < n_edges);
    const int s1 = has1 ? ei[e1] : s0;
    const int d1 = has1 ? ei[n_edges + e1] : d0;

    const h8v* __restrict__ xrow = reinterpret_cast<const h8v*>(xh);

    h8v a0 = xrow[(size_t)s0 * 16 + lane];
    h8v b0 = xrow[(size_t)d0 * 16 + lane];
    h8v a1 = xrow[(size_t)s1 * 16 + lane];
    h8v b1 = xrow[(size_t)d1 * 16 + lane];

    float acc0 = dot8(a0, b0, 0.f);
    float acc1 = dot8(a1, b1, 0.f);

    acc0 += __shfl_xor(acc0, 1, 16);
    acc0 += __shfl_xor(acc0, 2, 16);
    acc0 += __shfl_xor(acc0, 4, 16);
    acc0 += __shfl_xor(acc0, 8, 16);

    acc1 += __shfl_xor(acc1, 1, 16);
    acc1 += __shfl_xor(acc1, 2, 16);
    acc1 += __shfl_xor(acc1, 4, 16);
    acc1 += __shfl_xor(acc1, 8, 16);

    if (lane == 0) {
        out[e0] = sigmoid_fast(acc0);
        if (has1) out[e1] = sigmoid_fast(acc1);
    }
}

// ---------------- fp32 fallback (ws too small even for fp16 x) --------------
__global__ __launch_bounds__(256) void edge_dot_sigmoid_fp32_kernel(
    const float* __restrict__ x,
    const int* __restrict__ ei,
    float* __restrict__ out,
    int n_edges)
{
    const int lane = threadIdx.x & 15;
    const int e = blockIdx.x * 16 + (threadIdx.x >> 4);
    if (e >= n_edges) return;

    const int s = ei[e];
    const int d = ei[n_edges + e];

    const float4* sp = reinterpret_cast<const float4*>(x + (size_t)s * D_FEAT) + lane * 2;
    const float4* dp = reinterpret_cast<const float4*>(x + (size_t)d * D_FEAT) + lane * 2;

    float4 a0 = sp[0], a1 = sp[1], b0 = dp[0], b1 = dp[1];

    float acc = a0.x * b0.x + a0.y * b0.y + a0.z * b0.z + a0.w * b0.w
              + a1.x * b1.x + a1.y * b1.y + a1.z * b1.z + a1.w * b1.w;

    acc += __shfl_xor(acc, 1, 16);
    acc += __shfl_xor(acc, 2, 16);
    acc += __shfl_xor(acc, 4, 16);
    acc += __shfl_xor(acc, 8, 16);

    if (lane == 0) out[e] = sigmoid_fast(acc);
}

extern "C" void kernel_launch(void* const* d_in, const int* in_sizes, int n_in,
                              void* d_out, int out_size, void* d_ws, size_t ws_size,
                              hipStream_t stream) {
    const float* x   = (const float*)d_in[0];
    const int*   ei  = (const int*)d_in[1];
    float*       out = (float*)d_out;

    const int n_x     = in_sizes[0];        // n_nodes * 128
    const int n_edges = in_sizes[1] / 2;    // edge_index is [2, E]
    const int n_nodes = n_x / D_FEAT;

    // workspace layout: xh | sd(int2) | se(int) | hist | cursor | estart
    size_t off_xh   = 0;
    size_t off_sd   = ((size_t)n_x * 2 + 255) & ~(size_t)255;
    size_t off_se   = off_sd + (size_t)n_edges * 8;
    size_t off_hist = off_se + (size_t)n_edges * 4;
    size_t off_cur  = off_hist + NB * 4;
    size_t off_est  = off_cur + NB * 4;
    size_t need_full = off_est + 16 * 4;
    size_t need_fp16 = (size_t)n_x * 2;

    if (ws_size >= need_full) {
        __half* xh   = (__half*)((char*)d_ws + off_xh);
        int2*  sd     = (int2*)((char*)d_ws + off_sd);
        int*   se     = (int*)((char*)d_ws + off_se);
        int*   hist   = (int*)((char*)d_ws + off_hist);
        int*   cursor = (int*)((char*)d_ws + off_cur);
        int*   estart = (int*)((char*)d_ws + off_est);

        int shift = 0;
        while (((n_nodes - 1) >> shift) >= NB) shift++;

        hipMemsetAsync(hist, 0, NB * 4, stream);
        hist_kernel<<<128, 256, 0, stream>>>(ei, n_edges, shift, hist);
        scan_kernel<<<1, NB, 0, stream>>>(hist, cursor, estart, n_edges);
        scatter_kernel<<<(n_edges + SCH - 1) / SCH, 256, 0, stream>>>(
            ei, n_edges, shift, cursor, sd, se);

        int n_chunks = (n_x + 7) / 8;
        convert_x_fp16_kernel<<<(n_chunks + 255) / 256, 256, 0, stream>>>(x, xh, n_x);

        int npb = (n_edges / 8 + 8192 + 31) / 32 + 1;
        edge_dot_sigmoid_sorted_kernel<<<8 * npb, 256, 0, stream>>>(
            xh, sd, se, estart, out, npb);
    } else if (ws_size >= need_fp16) {
        __half* xh = (__half*)d_ws;
        int n_chunks = (n_x + 7) / 8;
        convert_x_fp16_kernel<<<(n_chunks + 255) / 256, 256, 0, stream>>>(x, xh, n_x);
        dim3 grid((n_edges + 31) / 32);
        edge_dot_sigmoid_fp16_kernel<<<grid, 256, 0, stream>>>(xh, ei, out, n_edges);
    } else {
        dim3 grid((n_edges + 15) / 16);
        edge_dot_sigmoid_fp32_kernel<<<grid, 256, 0, stream>>>(x, ei, out, n_edges);
    }
}

// Round 8
// 111.052 us; speedup vs baseline: 1.3183x; 1.3183x over previous
//
#include <hip/hip_runtime.h>
#include <hip/hip_fp16.h>
#include <math.h>

#define D_FEAT 128

// ROOFLINE NOTES (rounds 0-7):
// - Gather traffic floor (unsorted): 344 MB = per-XCD-L2 compulsory distinct
//   rows (8 XCDs x ~86.5K rows x 2 sides x 256 B). Measured FETCH matches.
// - Beyond-L2 random-gather BW ceiling: 3.74-3.76 TB/s (pinned across fp32/
//   fp16, 2/8-edge MLP variants, sorted/unsorted). 344 MB / 3.75 TB/s = 92 us;
//   this kernel runs 96 us (96%).
// - src-sorting cuts FETCH to ~200 MB but the sort pipeline costs 40-55 us
//   vs ~19 us saved (rounds 5-7: 134.5 / 146.4 us) -> structurally net-negative.
// - fp8 rows fail the 0.02 absmax threshold (dot error ~0.7 std).

typedef _Float16 f16x2 __attribute__((ext_vector_type(2)));
struct alignas(16) h8v { f16x2 h[4]; };   // 8 halves = 16B

__device__ __forceinline__ float dot8(const h8v& a, const h8v& b, float acc) {
#if __has_builtin(__builtin_amdgcn_fdot2)
#pragma unroll
    for (int k = 0; k < 4; ++k)
        acc = __builtin_amdgcn_fdot2(a.h[k], b.h[k], acc, false);
#else
#pragma unroll
    for (int k = 0; k < 4; ++k) {
        acc += (float)a.h[k].x * (float)b.h[k].x;
        acc += (float)a.h[k].y * (float)b.h[k].y;
    }
#endif
    return acc;
}

__device__ __forceinline__ float sigmoid_fast(float x) {
    // sigmoid(x) = 1/(1+e^-x); e^-x = 2^(-x*log2(e)) -> native v_exp_f32
    return 1.0f / (1.0f + __builtin_exp2f(-1.44269504f * x));
}

// ---------------- fp32 -> fp16 conversion of x into workspace ----------------
__global__ __launch_bounds__(256) void convert_x_fp16_kernel(
    const float* __restrict__ x, __half* __restrict__ xh, int n_elems)
{
    int i = blockIdx.x * blockDim.x + threadIdx.x;   // 8-element chunk id
    int base = i * 8;
    if (base >= n_elems) return;
    const float4* p = reinterpret_cast<const float4*>(x + base);
    float4 f0 = p[0];
    float4 f1 = p[1];
    __half2 h[4];
    h[0] = __floats2half2_rn(f0.x, f0.y);
    h[1] = __floats2half2_rn(f0.z, f0.w);
    h[2] = __floats2half2_rn(f1.x, f1.y);
    h[3] = __floats2half2_rn(f1.z, f1.w);
    *reinterpret_cast<float4*>(xh + base) = *reinterpret_cast<float4*>(h);
}

// ---------------- fp16 gather + dot + sigmoid ----------------
// Best measured structure: 16-lane group per edge, 2 edges per group per
// block so all 4 row-loads (16B/lane each) are in flight before any
// dependent math; dot via v_dot2_f32_f16; 4-step shfl_xor reduce.
__global__ __launch_bounds__(256) void edge_dot_sigmoid_fp16_kernel(
    const __half* __restrict__ xh,
    const int* __restrict__ ei,
    float* __restrict__ out,
    int n_edges)
{
    const int lane = threadIdx.x & 15;
    const int grp  = threadIdx.x >> 4;            // 16 groups per block
    const int base = blockIdx.x * 32;             // 32 edges per block
    const int e0 = base + grp;
    const int e1 = base + 16 + grp;

    if (e0 >= n_edges) return;

    const int s0 = ei[e0];
    const int d0 = ei[n_edges + e0];
    const bool has1 = (e1 < n_edges);
    const int s1 = has1 ? ei[e1] : s0;
    const int d1 = has1 ? ei[n_edges + e1] : d0;

    const h8v* __restrict__ xrow = reinterpret_cast<const h8v*>(xh); // 16/row

    h8v a0 = xrow[(size_t)s0 * 16 + lane];
    h8v b0 = xrow[(size_t)d0 * 16 + lane];
    h8v a1 = xrow[(size_t)s1 * 16 + lane];
    h8v b1 = xrow[(size_t)d1 * 16 + lane];

    float acc0 = dot8(a0, b0, 0.f);
    float acc1 = dot8(a1, b1, 0.f);

    acc0 += __shfl_xor(acc0, 1, 16);
    acc0 += __shfl_xor(acc0, 2, 16);
    acc0 += __shfl_xor(acc0, 4, 16);
    acc0 += __shfl_xor(acc0, 8, 16);

    acc1 += __shfl_xor(acc1, 1, 16);
    acc1 += __shfl_xor(acc1, 2, 16);
    acc1 += __shfl_xor(acc1, 4, 16);
    acc1 += __shfl_xor(acc1, 8, 16);

    if (lane == 0) {
        out[e0] = sigmoid_fast(acc0);
        if (has1) out[e1] = sigmoid_fast(acc1);
    }
}

// ---------------- fp32 fallback (used only if ws too small) ------------------
__global__ __launch_bounds__(256) void edge_dot_sigmoid_fp32_kernel(
    const float* __restrict__ x,
    const int* __restrict__ ei,
    float* __restrict__ out,
    int n_edges)
{
    const int lane = threadIdx.x & 15;
    const int e = blockIdx.x * 16 + (threadIdx.x >> 4);
    if (e >= n_edges) return;

    const int s = ei[e];
    const int d = ei[n_edges + e];

    const float4* sp = reinterpret_cast<const float4*>(x + (size_t)s * D_FEAT) + lane * 2;
    const float4* dp = reinterpret_cast<const float4*>(x + (size_t)d * D_FEAT) + lane * 2;

    float4 a0 = sp[0], a1 = sp[1], b0 = dp[0], b1 = dp[1];

    float acc = a0.x * b0.x + a0.y * b0.y + a0.z * b0.z + a0.w * b0.w
              + a1.x * b1.x + a1.y * b1.y + a1.z * b1.z + a1.w * b1.w;

    acc += __shfl_xor(acc, 1, 16);
    acc += __shfl_xor(acc, 2, 16);
    acc += __shfl_xor(acc, 4, 16);
    acc += __shfl_xor(acc, 8, 16);

    if (lane == 0) out[e] = sigmoid_fast(acc);
}

extern "C" void kernel_launch(void* const* d_in, const int* in_sizes, int n_in,
                              void* d_out, int out_size, void* d_ws, size_t ws_size,
                              hipStream_t stream) {
    const float* x   = (const float*)d_in[0];
    const int*   ei  = (const int*)d_in[1];
    float*       out = (float*)d_out;

    const int n_x     = in_sizes[0];        // n_nodes * 128
    const int n_edges = in_sizes[1] / 2;    // edge_index is [2, E]

    const size_t need = (size_t)n_x * sizeof(__half);
    if (ws_size >= need) {
        __half* xh = (__half*)d_ws;
        int n_chunks = (n_x + 7) / 8;
        convert_x_fp16_kernel<<<(n_chunks + 255) / 256, 256, 0, stream>>>(x, xh, n_x);
        dim3 grid((n_edges + 31) / 32);
        edge_dot_sigmoid_fp16_kernel<<<grid, 256, 0, stream>>>(xh, ei, out, n_edges);
    } else {
        dim3 grid((n_edges + 15) / 16);
        edge_dot_sigmoid_fp32_kernel<<<grid, 256, 0, stream>>>(x, ei, out, n_edges);
    }
}